// Round 8
// baseline (727.963 us; speedup 1.0000x reference)
//
#include <hip/hip_runtime.h>

// Layer3bitWithZero: out = A @ (q * s + z), groupwise dequant (GROUPSIZE=64)
// Wire dtypes (fp16 canonicalized to f32): A (2048,4096) f32; q (4096,11264) i32;
// s,z (64,11264) f32; out (2048,11264) f32.  Compute: fp16 MFMA.
// Round 8: XCD-owns-A-panel. BM=256 (A panel = 4 MB = one XCD L2), bm = bid&7
// (hw XCD round-robin) -> each XCD pins one A panel in L2, streams Q via LLC.
// 512 thr, 8 waves (4m x 2n, 64x64 each), dbuf LDS 96 KB, async-STAGE split.

#define M_DIM 2048
#define N_DIM 11264
#define K_DIM 4096

constexpr int BM = 256, BN = 128, BK = 64;
constexpr int GRID_M = M_DIM / BM;       // 8  == #XCDs
constexpr int GRID_N = N_DIM / BN;       // 88
constexpr int NBLK = GRID_M * GRID_N;    // 704
constexpr int KTILES = K_DIM / BK;       // 64

typedef __attribute__((ext_vector_type(8))) _Float16 half8;
typedef __attribute__((ext_vector_type(2))) _Float16 half2v;
typedef __attribute__((ext_vector_type(4))) float floatx4;

static __device__ __forceinline__ half2v pkrtz(float a, float b) {
    return __builtin_bit_cast(half2v, __builtin_amdgcn_cvt_pkrtz(a, b));
}

__global__ void __launch_bounds__(512, 1)
l3z_gemm(const float* __restrict__ A, const int* __restrict__ Q,
         const float* __restrict__ S, const float* __restrict__ Z,
         float* __restrict__ out)
{
    // A tile: strip-major [m][ks'] , ks' = ks ^ (m&7)  (XOR swizzle, 8x8-fp16 strips)
    // B tile: strip-major [ks][n]
    __shared__ _Float16 ldsA[2][BM * BK];   // 2 x 32 KiB
    __shared__ _Float16 ldsB[2][BK * BN];   // 2 x 16 KiB

    // XCD mapping: hw assigns bid round-robin by XCD -> bm = bid&7 pins one
    // 4 MB A panel per XCD L2; bn walks columns.
    int bid = blockIdx.x;
    int bm = bid & 7;
    int bn = bid >> 3;
    int m0 = bm * BM, n0 = bn * BN;

    int tid  = threadIdx.x;
    int lane = tid & 63;
    int wv   = tid >> 6;         // 0..7
    int wr   = (wv >> 1) * 64;   // 0,64,128,192
    int wc   = (wv & 1) * 64;    // 0,64

    // B staging coords: thread -> fixed column n, 16-k segment
    int nB   = tid & 127;
    int kb0  = (tid >> 7) * 16;          // 0,16,32,48
    const int* qcol = Q + n0 + nB;

    floatx4 acc[4][4];
#pragma unroll
    for (int i = 0; i < 4; ++i)
#pragma unroll
        for (int j = 0; j < 4; ++j)
            acc[i][j] = (floatx4){0.f, 0.f, 0.f, 0.f};

    // ---- prefetch registers (held across compute) ----
    float4 apre[4][2];     // 4 strips x 8 f32  (256*64/512 = 32 f32/thread)
    int    bpre[2][8];     // 16 q values       (64*128/512 = 16 /thread)
    float  spre, zpre;

    auto issue = [&](int t) {
        int k0 = t * BK;
#pragma unroll
        for (int i = 0; i < 4; ++i) {
            int slot = i * 512 + tid;
            int m  = slot >> 3;          // 0..255
            int ks = tid & 7;
            const float* src = A + (size_t)(m0 + m) * K_DIM + (k0 + ks * 8);
            apre[i][0] = *(const float4*)(src);
            apre[i][1] = *(const float4*)(src + 4);
        }
        spre = S[(size_t)t * N_DIM + n0 + nB];
        zpre = Z[(size_t)t * N_DIM + n0 + nB];
#pragma unroll
        for (int i = 0; i < 2; ++i) {
            int kb = kb0 + i * 8;
#pragma unroll
            for (int j = 0; j < 8; ++j)
                bpre[i][j] = qcol[(size_t)(k0 + kb + j) * N_DIM];
        }
    };

    auto writeLds = [&](int buf) {
#pragma unroll
        for (int i = 0; i < 4; ++i) {
            int slot = i * 512 + tid;
            int m  = slot >> 3;
            int ks = tid & 7;
            // A values are fp16-representable -> RTZ pack is exact.
            half2v p0 = pkrtz(apre[i][0].x, apre[i][0].y);
            half2v p1 = pkrtz(apre[i][0].z, apre[i][0].w);
            half2v p2 = pkrtz(apre[i][1].x, apre[i][1].y);
            half2v p3 = pkrtz(apre[i][1].z, apre[i][1].w);
            half8 h = { p0[0], p0[1], p1[0], p1[1], p2[0], p2[1], p3[0], p3[1] };
            int ksx = ks ^ (m & 7);                       // XOR swizzle (write side)
            *(half8*)(&ldsA[buf][(size_t)((m << 3) + ksx) * 8]) = h;
        }
#pragma unroll
        for (int i = 0; i < 2; ++i) {
            int kb = kb0 + i * 8;
            half8 w;
#pragma unroll
            for (int j = 0; j < 8; ++j)
                w[j] = (_Float16)fmaf((float)bpre[i][j], spre, zpre);  // RTNE
            int ks = kb >> 3;
            *(half8*)(&ldsB[buf][(size_t)(ks * 128 + nB) * 8]) = w;
        }
    };

    // ---------------- prologue ----------------
    issue(0);
    writeLds(0);
    __syncthreads();

    int cur = 0;
    for (int t = 0; t < KTILES; ++t) {
        if (t + 1 < KTILES)
            issue(t + 1);                 // loads in flight during compute

        const _Float16* lA = ldsA[cur];
        const _Float16* lB = ldsB[cur];
#pragma unroll
        for (int half = 0; half < 2; ++half) {
            int ksb = half * 4 + (lane >> 4);
            half8 af[4], bfr[4];
#pragma unroll
            for (int mf = 0; mf < 4; ++mf) {
                int r = wr + mf * 16 + (lane & 15);       // 0..255
                int ksx = ksb ^ (r & 7);                  // XOR swizzle (read side)
                af[mf] = *(const half8*)(lA + (size_t)((r << 3) + ksx) * 8);
            }
#pragma unroll
            for (int nf = 0; nf < 4; ++nf) {
                int c = wc + nf * 16 + (lane & 15);       // 0..127
                bfr[nf] = *(const half8*)(lB + (size_t)(ksb * 128 + c) * 8);
            }
#pragma unroll
            for (int mf = 0; mf < 4; ++mf)
#pragma unroll
                for (int nf = 0; nf < 4; ++nf)
                    acc[mf][nf] = __builtin_amdgcn_mfma_f32_16x16x32_f16(
                        af[mf], bfr[nf], acc[mf][nf], 0, 0, 0);
        }

        if (t + 1 < KTILES) {
            writeLds(cur ^ 1);            // waits on its own loads only
            __syncthreads();              // one barrier per tile
            cur ^= 1;
        }
    }

    // ---------------- epilogue ----------------
    // C/D layout (dtype-independent): col = lane&15, row = (lane>>4)*4 + reg
    int rbase = m0 + wr + ((lane >> 4) << 2);
    int cbase = n0 + wc + (lane & 15);
#pragma unroll
    for (int mf = 0; mf < 4; ++mf)
#pragma unroll
        for (int nf = 0; nf < 4; ++nf)
#pragma unroll
            for (int rr = 0; rr < 4; ++rr) {
                int row = rbase + mf * 16 + rr;
                int col = cbase + nf * 16;
                out[(size_t)row * N_DIM + col] = acc[mf][nf][rr];
            }
}

extern "C" void kernel_launch(void* const* d_in, const int* in_sizes, int n_in,
                              void* d_out, int out_size, void* d_ws, size_t ws_size,
                              hipStream_t stream) {
    const float* A = (const float*)d_in[0];
    const int*   Q = (const int*)d_in[1];
    const float* S = (const float*)d_in[2];
    const float* Z = (const float*)d_in[3];
    float* O = (float*)d_out;

    l3z_gemm<<<dim3(NBLK), dim3(512), 0, stream>>>(A, Q, S, Z, O);
}

// Round 9
// 519.519 us; speedup vs baseline: 1.4012x; 1.4012x over previous
//
#include <hip/hip_runtime.h>

// Layer3bitWithZero: out = A @ (q * s + z), groupwise dequant (GROUPSIZE=64)
// Wire dtypes (fp16 canonicalized to f32): A (2048,4096) f32; q (4096,11264) i32;
// s,z (64,11264) f32; out (2048,11264) f32.
// Round 9: pre-pass factorization.
//   xform_a: A -> fp16, tiled+XOR-swizzled 16KB LDS-images in ws
//   xform_w: dequant q*s+z -> fp16 W, tiled B-images in ws
//   l3z_mm : pure fp16 MFMA GEMM, m97 structure, global_load_lds staging
// Fallback to fused kernel if ws_size < 110 MB.

#define M_DIM 2048
#define N_DIM 11264
#define K_DIM 4096

constexpr int BM = 128, BN = 128, BK = 64;
constexpr int GRID_M = M_DIM / BM;       // 16
constexpr int GRID_N = N_DIM / BN;       // 88
constexpr int NBLK = GRID_M * GRID_N;    // 1408 = 8*176
constexpr int KTILES = K_DIM / BK;       // 64
constexpr int TILE_ELE = BM * BK;        // 8192 fp16 = 16 KB per image tile

typedef __attribute__((ext_vector_type(8))) _Float16 half8;
typedef __attribute__((ext_vector_type(2))) _Float16 half2v;
typedef __attribute__((ext_vector_type(4))) float floatx4;

static __device__ __forceinline__ half2v pkrtz(float a, float b) {
    return __builtin_bit_cast(half2v, __builtin_amdgcn_cvt_pkrtz(a, b));
}

// ---------------------------------------------------------------------------
// Transform A: per tile (bm,t) write 128m x 64k fp16 as the LDS image.
// Image layout (fp16 idx): mg*512 + (ks^mr)*64 + mr*8 + e, m = mg*8+mr.
// ---------------------------------------------------------------------------
__global__ void __launch_bounds__(256)
xform_a(const float* __restrict__ A, _Float16* __restrict__ aimg)
{
    int tile = blockIdx.x;               // bm*64 + t
    int bm = tile >> 6, t = tile & 63;
    int m0 = bm * BM, k0 = t * BK;
    int tid = threadIdx.x;
#pragma unroll
    for (int i = 0; i < 4; ++i) {
        int strip = i * 256 + tid;       // 0..1023
        int mg = strip >> 6, ksx = (strip >> 3) & 7, mr = strip & 7;
        int ks = ksx ^ mr;
        int m  = mg * 8 + mr;
        const float* src = A + (size_t)(m0 + m) * K_DIM + k0 + ks * 8;
        float4 f0 = *(const float4*)src;
        float4 f1 = *(const float4*)(src + 4);
        half2v p0 = pkrtz(f0.x, f0.y), p1 = pkrtz(f0.z, f0.w);
        half2v p2 = pkrtz(f1.x, f1.y), p3 = pkrtz(f1.z, f1.w);
        half8 h = { p0[0], p0[1], p1[0], p1[1], p2[0], p2[1], p3[0], p3[1] };
        *(half8*)(aimg + (size_t)tile * TILE_ELE + strip * 8) = h;
    }
}

// ---------------------------------------------------------------------------
// Transform W: per tile (bn,t) dequant 64k x 128n -> fp16 B image.
// Image layout (fp16 idx): ks*1024 + n*8 + e  (strip = col-segment of 8 k).
// ---------------------------------------------------------------------------
__global__ void __launch_bounds__(256)
xform_w(const int* __restrict__ Q, const float* __restrict__ S,
        const float* __restrict__ Z, _Float16* __restrict__ wimg)
{
    int tile = blockIdx.x;               // bn*64 + t
    int bn = tile >> 6, t = tile & 63;
    int n0 = bn * BN, k0 = t * BK;
    int tid = threadIdx.x;
    int n = tid & 127;
    int ksb = (tid >> 7) * 4;
    float sf = S[(size_t)t * N_DIM + n0 + n];
    float zf = Z[(size_t)t * N_DIM + n0 + n];
    const int* qcol = Q + (size_t)k0 * N_DIM + n0 + n;
#pragma unroll
    for (int i = 0; i < 4; ++i) {
        int ks = ksb + i;
        half8 w;
#pragma unroll
        for (int j = 0; j < 8; ++j) {
            int v = qcol[(size_t)(ks * 8 + j) * N_DIM];
            w[j] = (_Float16)fmaf((float)v, sf, zf);   // RTNE, same as passing rounds
        }
        *(half8*)(wimg + (size_t)tile * TILE_ELE + ks * 1024 + n * 8) = w;
    }
}

// ---------------------------------------------------------------------------
// GEMM: m97 structure. 256 thr, 4 waves (2x2 of 64x64), single-buffer LDS,
// global_load_lds staging of pre-built images, 2 barriers/tile.
// ---------------------------------------------------------------------------
__global__ void __launch_bounds__(256)
l3z_mm(const _Float16* __restrict__ aimg, const _Float16* __restrict__ wimg,
       float* __restrict__ out)
{
    __shared__ _Float16 ldsA[TILE_ELE];  // 16 KiB
    __shared__ _Float16 ldsB[TILE_ELE];  // 16 KiB

    int bid = blockIdx.x;
    int vid = (bid & 7) * (NBLK / 8) + (bid >> 3);   // XCD-bijective
    int bm = vid % GRID_M;
    int bn = vid / GRID_M;

    int tid  = threadIdx.x;
    int lane = tid & 63;
    int wv   = tid >> 6;
    int wr   = (wv >> 1) * 64;
    int wc   = (wv & 1) * 64;

    const _Float16* atile = aimg + (size_t)(bm * KTILES) * TILE_ELE;
    const _Float16* wtile = wimg + (size_t)(bn * KTILES) * TILE_ELE;

    floatx4 acc[4][4];
#pragma unroll
    for (int i = 0; i < 4; ++i)
#pragma unroll
        for (int j = 0; j < 4; ++j)
            acc[i][j] = (floatx4){0.f, 0.f, 0.f, 0.f};

    auto stage = [&](int t) {
        const _Float16* at = atile + (size_t)t * TILE_ELE;
        const _Float16* wt = wtile + (size_t)t * TILE_ELE;
#pragma unroll
        for (int i = 0; i < 4; ++i) {
            int seg = (wv * 4 + i) * 512;            // fp16 units, 1 KB per instr
            __builtin_amdgcn_global_load_lds(
                (const __attribute__((address_space(1))) void*)(at + seg + lane * 8),
                (__attribute__((address_space(3))) void*)(ldsA + seg), 16, 0, 0);
        }
#pragma unroll
        for (int i = 0; i < 4; ++i) {
            int seg = (wv * 4 + i) * 512;
            __builtin_amdgcn_global_load_lds(
                (const __attribute__((address_space(1))) void*)(wt + seg + lane * 8),
                (__attribute__((address_space(3))) void*)(ldsB + seg), 16, 0, 0);
        }
    };

    stage(0);
    __syncthreads();

    for (int t = 0; t < KTILES; ++t) {
#pragma unroll
        for (int half = 0; half < 2; ++half) {
            int ksb = half * 4 + (lane >> 4);
            half8 af[4], bfr[4];
#pragma unroll
            for (int mf = 0; mf < 4; ++mf) {
                int r = wr + mf * 16 + (lane & 15);
                int idx = (r >> 3) * 512 + (ksb ^ (r & 7)) * 64 + (r & 7) * 8;
                af[mf] = *(const half8*)(ldsA + idx);
            }
#pragma unroll
            for (int nf = 0; nf < 4; ++nf) {
                int c = wc + nf * 16 + (lane & 15);
                bfr[nf] = *(const half8*)(ldsB + (ksb * 1024 + c * 8));
            }
#pragma unroll
            for (int mf = 0; mf < 4; ++mf)
#pragma unroll
                for (int nf = 0; nf < 4; ++nf)
                    acc[mf][nf] = __builtin_amdgcn_mfma_f32_16x16x32_f16(
                        af[mf], bfr[nf], acc[mf][nf], 0, 0, 0);
        }
        if (t + 1 < KTILES) {
            __syncthreads();             // done reading
            stage(t + 1);
            __syncthreads();             // staged (drains vmcnt)
        }
    }

    int m0 = bm * BM, n0 = bn * BN;
    int rbase = m0 + wr + ((lane >> 4) << 2);
    int cbase = n0 + wc + (lane & 15);
#pragma unroll
    for (int mf = 0; mf < 4; ++mf)
#pragma unroll
        for (int nf = 0; nf < 4; ++nf)
#pragma unroll
            for (int rr = 0; rr < 4; ++rr)
                out[(size_t)(rbase + mf * 16 + rr) * N_DIM + (cbase + nf * 16)] =
                    acc[mf][nf][rr];
}

// ---------------------------------------------------------------------------
// Fallback (round-7 style fused kernel) if ws is too small.
// ---------------------------------------------------------------------------
__global__ void __launch_bounds__(256, 2)
l3z_fused(const float* __restrict__ A, const int* __restrict__ Q,
          const float* __restrict__ S, const float* __restrict__ Z,
          float* __restrict__ out)
{
    __shared__ _Float16 ldsA[2][BM * BK];
    __shared__ _Float16 ldsB[2][BK * BN];
    int bid = blockIdx.x;
    int vid = (bid & 7) * (NBLK / 8) + (bid >> 3);
    int bm = vid % GRID_M, bn = vid / GRID_M;
    int m0 = bm * BM, n0 = bn * BN;
    int tid = threadIdx.x, lane = tid & 63, wv = tid >> 6;
    int wr = (wv >> 1) * 64, wc = (wv & 1) * 64;
    int nB = tid & 127, kb0 = (tid >> 7) * 8;
    const int* qcol = Q + n0 + nB;
    floatx4 acc[4][4];
#pragma unroll
    for (int i = 0; i < 4; ++i)
#pragma unroll
        for (int j = 0; j < 4; ++j) acc[i][j] = (floatx4){0.f,0.f,0.f,0.f};
    float4 apre[4][2]; int bpre[4][8]; float spre, zpre;
    auto issue = [&](int t) {
        int k0 = t * BK;
#pragma unroll
        for (int i = 0; i < 4; ++i) {
            int slot = i * 256 + tid; int m = slot >> 3; int ks = tid & 7;
            const float* src = A + (size_t)(m0 + m) * K_DIM + (k0 + ks * 8);
            apre[i][0] = *(const float4*)(src); apre[i][1] = *(const float4*)(src + 4);
        }
        spre = S[(size_t)t * N_DIM + n0 + nB]; zpre = Z[(size_t)t * N_DIM + n0 + nB];
#pragma unroll
        for (int i = 0; i < 4; ++i) { int kb = kb0 + i * 16;
#pragma unroll
            for (int j = 0; j < 8; ++j) bpre[i][j] = qcol[(size_t)(k0 + kb + j) * N_DIM]; }
    };
    auto writeLds = [&](int buf) {
#pragma unroll
        for (int i = 0; i < 4; ++i) {
            int slot = i * 256 + tid; int m = slot >> 3; int ks = tid & 7;
            half2v p0 = pkrtz(apre[i][0].x, apre[i][0].y), p1 = pkrtz(apre[i][0].z, apre[i][0].w);
            half2v p2 = pkrtz(apre[i][1].x, apre[i][1].y), p3 = pkrtz(apre[i][1].z, apre[i][1].w);
            half8 h = { p0[0],p0[1],p1[0],p1[1],p2[0],p2[1],p3[0],p3[1] };
            *(half8*)(&ldsA[buf][(size_t)((m << 3) + (ks ^ (m & 7))) * 8]) = h;
        }
#pragma unroll
        for (int i = 0; i < 4; ++i) { int kb = kb0 + i * 16; half8 w;
#pragma unroll
            for (int j = 0; j < 8; ++j) w[j] = (_Float16)fmaf((float)bpre[i][j], spre, zpre);
            *(half8*)(&ldsB[buf][(size_t)((kb >> 3) * 128 + nB) * 8]) = w; }
    };
    issue(0); writeLds(0); __syncthreads();
    int cur = 0;
    for (int t = 0; t < KTILES; ++t) {
        if (t + 1 < KTILES) issue(t + 1);
        const _Float16* lA = ldsA[cur]; const _Float16* lB = ldsB[cur];
#pragma unroll
        for (int half = 0; half < 2; ++half) {
            int ksb = half * 4 + (lane >> 4); half8 af[4], bfr[4];
#pragma unroll
            for (int mf = 0; mf < 4; ++mf) { int r = wr + mf * 16 + (lane & 15);
                af[mf] = *(const half8*)(lA + (size_t)((r << 3) + (ksb ^ (r & 7))) * 8); }
#pragma unroll
            for (int nf = 0; nf < 4; ++nf) { int c = wc + nf * 16 + (lane & 15);
                bfr[nf] = *(const half8*)(lB + (size_t)(ksb * 128 + c) * 8); }
#pragma unroll
            for (int mf = 0; mf < 4; ++mf)
#pragma unroll
                for (int nf = 0; nf < 4; ++nf)
                    acc[mf][nf] = __builtin_amdgcn_mfma_f32_16x16x32_f16(af[mf], bfr[nf], acc[mf][nf], 0, 0, 0);
        }
        if (t + 1 < KTILES) { writeLds(cur ^ 1); __syncthreads(); cur ^= 1; }
    }
    int rbase = m0 + wr + ((lane >> 4) << 2), cbase = n0 + wc + (lane & 15);
#pragma unroll
    for (int mf = 0; mf < 4; ++mf)
#pragma unroll
        for (int nf = 0; nf < 4; ++nf)
#pragma unroll
            for (int rr = 0; rr < 4; ++rr)
                out[(size_t)(rbase + mf * 16 + rr) * N_DIM + (cbase + nf * 16)] = acc[mf][nf][rr];
}

extern "C" void kernel_launch(void* const* d_in, const int* in_sizes, int n_in,
                              void* d_out, int out_size, void* d_ws, size_t ws_size,
                              hipStream_t stream) {
    const float* A = (const float*)d_in[0];
    const int*   Q = (const int*)d_in[1];
    const float* S = (const float*)d_in[2];
    const float* Z = (const float*)d_in[3];
    float* O = (float*)d_out;

    size_t aElems = (size_t)GRID_M * KTILES * TILE_ELE;   // 8.39M fp16 = 16.8 MB
    size_t wElems = (size_t)GRID_N * KTILES * TILE_ELE;   // 46.1M fp16 = 92.3 MB
    size_t need = (aElems + wElems) * sizeof(_Float16);

    if (ws_size >= need) {
        _Float16* aimg = (_Float16*)d_ws;
        _Float16* wimg = aimg + aElems;
        xform_a<<<dim3(GRID_M * KTILES), dim3(256), 0, stream>>>(A, aimg);
        xform_w<<<dim3(GRID_N * KTILES), dim3(256), 0, stream>>>(Q, S, Z, wimg);
        l3z_mm <<<dim3(NBLK),            dim3(256), 0, stream>>>(aimg, wimg, O);
    } else {
        l3z_fused<<<dim3(NBLK), dim3(256), 0, stream>>>(A, Q, S, Z, O);
    }
}